// Round 9
// baseline (97.777 us; speedup 1.0000x reference)
//
#include <hip/hip_runtime.h>
#include <math.h>

// Residual 4-level E8-root VQ — analytic argmin + decomposed exact fallbacks,
// 2 rows/thread, ONE branch region per level (R9).
//
// Outputs (concat, all float32 in d_out):
//   [0, 8N)          quantized_ste = (qsum + x) - x   (matches jnp rounding)
//   [8N, 12N)        idx_stack[4][N] as float (values 0..239)
//   [12N]            qerr = mean((x - qsum)^2)
//
// ---- Analytic argmin (R4/R5, verified absmax=0) ----
// Reference: d2[j] = fl(fl(res2+2) - fl(2*dot_j)), dot_j sequential k=0..7;
// argmin, first-index tie-break on ROUNDED values.
//   T1 best: two largest |r_k| (A1,A2), signs of those coords.
//   T2 best: sign mask of r; odd parity flips the smallest-|r_k| bit.
// Error budget (u = 2^-24, M = res2 + 2 + 2*Sabs): ref d2 deviates from
// analytic by <= 2.75u*M; compare slop <= 5.5u*M; margin measurement error
// <= 3.5u*M. thr = 2^-20*M = 16u*M: passing margin -> true gap >= 12.5u*M
// > 5.5u*M -> rounding can neither reorder nor create a rounded tie.
//
// ---- Fallback decomposition (R6/R7, verified absmax=0) ----
//   !a1: if Amin > thr -> 28-pair best-sign EXACT scan (wrong signs trail by
//        2*Amin > 2thr); else full 112 exact scan (rolled).
//   !a2 odd: if 2*Amin2 > thr -> argmin is a SINGLE-BIT flip, 8 exact
//        seq-sum d2s, tie-break smaller t; else full 128 scan (rolled).
//   !a2 even: full 128 scan.
//   !c with a2: exact ref d2 of analytic T2 candidate (seq |h| sum, Amin
//        term negated iff odd parity; bitwise == reference).
//   pick: c ? (dT1>dT2 ? i1:i2) : (d1<=d2x ? i1:i2)  ('<=' == first-index).
//
// ---- R9 structural change (perf only; all numerics verbatim from R7/R8) ----
// Previous: ~6-8 wave-uniform branch regions per level (3 __any x 2 slots +
// guards). Each region is a scheduler fence -> slot0/slot1 sort networks
// couldn't interleave (VALUBusy 31%), and inlined fallbacks bloat the loop
// body. Now: both slots' analytic paths run straight-line (clamp-loaded
// rows, no act branches in compute), ONE __any gate per level covers all
// six conditions, full scans are ROLLED (tiny static code). Fallback lanes
// gather root from global roots (L2-hot) and update qsum/resid in-region.
//
// ---- Exact-path numerics (verified absmax=0 R1/R4/R5/R7/R8) ----
//  - r2[j] == 2.0 exactly; d2 = fmaf(+-2, dot, s) == fl(s - fl(2*dot)).
//  - clip(.,0) dropped: at most one root can have rounded d2 <= 0.
//  - res2: numpy pairwise tree; fp contract OFF everywhere.

__global__ __launch_bounds__(256) void e8_quant_kernel(
    const float* __restrict__ x, const float* __restrict__ roots,
    float* __restrict__ out, float* __restrict__ partials, int nrow) {
#pragma clang fp contract(off)
  __shared__ float wredA[4];
  __shared__ float wredB[4];

  const int row0 = blockIdx.x * 512 + threadIdx.x;
  const int row1 = row0 + 256;
  const bool act[2] = {row0 < nrow, row1 < nrow};
  const int rl[2] = {act[0] ? row0 : nrow - 1, act[1] ? row1 : nrow - 1};
  float* out_idx = out + (size_t)nrow * 8;
  float* op[2] = {out_idx + row0, out_idx + row1};

  float xr[2][8], qs[2][8], rr[2][8];
#pragma unroll
  for (int sl = 0; sl < 2; ++sl) {
    const float4 xa = *(const float4*)(x + (size_t)rl[sl] * 8);
    const float4 xb = *(const float4*)(x + (size_t)rl[sl] * 8 + 4);
    xr[sl][0] = xa.x; xr[sl][1] = xa.y; xr[sl][2] = xa.z; xr[sl][3] = xa.w;
    xr[sl][4] = xb.x; xr[sl][5] = xb.y; xr[sl][6] = xb.z; xr[sl][7] = xb.w;
#pragma unroll
    for (int k = 0; k < 8; ++k) { qs[sl][k] = 0.f; rr[sl][k] = xr[sl][k]; }
  }

#pragma unroll 1
  for (int lvl = 0; lvl < 4; ++lvl) {
    float s_[2], thr_[2], dT1_[2], dT2_[2], Amn_[2], Amn2_[2];
    int t1_[2], t2_[2], pk_[2], bi_[2];
    bool a1_[2], a2_[2], c_[2], fell_[2], pT1_[2];

    // ======== ANALYTIC, both slots, straight-line (no branches) ========
#pragma unroll
    for (int sl = 0; sl < 2; ++sl) {
      // res2, numpy pairwise order
      float q[8];
#pragma unroll
      for (int k = 0; k < 8; ++k) q[k] = rr[sl][k] * rr[sl][k];
      const float res2 = ((q[0] + q[1]) + (q[2] + q[3])) +
                         ((q[4] + q[5]) + (q[6] + q[7]));
      const float s = res2 + 2.0f;

      float mg[8];
      int sb[8];
#pragma unroll
      for (int k = 0; k < 8; ++k) {
        const unsigned u = __float_as_uint(rr[sl][k]);
        mg[k] = __uint_as_float(u & 0x7fffffffu);
        sb[k] = (int)(u >> 31);
      }
      const int msk = sb[0] | (sb[1] << 1) | (sb[2] << 2) | (sb[3] << 3) |
                      (sb[4] << 4) | (sb[5] << 5) | (sb[6] << 6) |
                      (sb[7] << 7);
      const int par = __popc(msk) & 1;
      const float Sabs = ((mg[0] + mg[1]) + (mg[2] + mg[3])) +
                         ((mg[4] + mg[5]) + (mg[6] + mg[7]));

      const int K0 = 0 | (sb[0] << 3), K1 = 1 | (sb[1] << 3),
                K2 = 2 | (sb[2] << 3), K3 = 3 | (sb[3] << 3),
                K4 = 4 | (sb[4] << 3), K5 = 5 | (sb[5] << 3),
                K6 = 6 | (sb[6] << 3), K7 = 7 | (sb[7] << 3);

      // top-3 (A1>=A2>=A3) + keys for A1,A2
      const bool g01 = mg[1] > mg[0];
      const float h01 = fmaxf(mg[0], mg[1]), l01 = fminf(mg[0], mg[1]);
      const int hk01 = g01 ? K1 : K0, lk01 = g01 ? K0 : K1;
      const bool g23 = mg[3] > mg[2];
      const float h23 = fmaxf(mg[2], mg[3]), l23 = fminf(mg[2], mg[3]);
      const int hk23 = g23 ? K3 : K2, lk23 = g23 ? K2 : K3;
      const bool g45 = mg[5] > mg[4];
      const float h45 = fmaxf(mg[4], mg[5]), l45 = fminf(mg[4], mg[5]);
      const int hk45 = g45 ? K5 : K4, lk45 = g45 ? K4 : K5;
      const bool g67 = mg[7] > mg[6];
      const float h67 = fmaxf(mg[6], mg[7]), l67 = fminf(mg[6], mg[7]);
      const int hk67 = g67 ? K7 : K6, lk67 = g67 ? K6 : K7;
      const bool qg0 = h23 > h01;
      const float qh0 = fmaxf(h01, h23);
      const int qhk0 = qg0 ? hk23 : hk01;
      const float sA0 = qg0 ? l23 : l01;
      const int sAk0 = qg0 ? lk23 : lk01;
      const float sB0 = qg0 ? h01 : h23;
      const int sBk0 = qg0 ? hk01 : hk23;
      const float loL0 = qg0 ? l01 : l23;
      const bool qx0 = sB0 > sA0;
      const float qs0v = fmaxf(sA0, sB0);
      const int qsk0 = qx0 ? sBk0 : sAk0;
      const float qt0 = qx0 ? fmaxf(sA0, loL0) : sB0;
      const bool qg1 = h67 > h45;
      const float qh1 = fmaxf(h45, h67);
      const int qhk1 = qg1 ? hk67 : hk45;
      const float sA1 = qg1 ? l67 : l45;
      const int sAk1 = qg1 ? lk67 : lk45;
      const float sB1 = qg1 ? h45 : h67;
      const int sBk1 = qg1 ? hk45 : hk67;
      const float loL1 = qg1 ? l45 : l67;
      const bool qx1 = sB1 > sA1;
      const float qs1v = fmaxf(sA1, sB1);
      const int qsk1 = qx1 ? sBk1 : sAk1;
      const float qt1 = qx1 ? fmaxf(sA1, loL1) : sB1;
      const bool fg = qh1 > qh0;
      const float A1v = fmaxf(qh0, qh1);
      const int A1K = fg ? qhk1 : qhk0;
      const float fA = fg ? qs1v : qs0v;
      const int fAk = fg ? qsk1 : qsk0;
      const float fB = fg ? qh0 : qh1;
      const int fBk = fg ? qhk0 : qhk1;
      const float tW = fg ? qt1 : qt0;
      const float sL = fg ? qs0v : qs1v;
      const bool fh = fB > fA;
      const float A2v = fmaxf(fA, fB);
      const int A2K = fh ? fBk : fAk;
      const float A3v = fh ? fmaxf(fA, sL) : fmaxf(tW, fB);

      // bottom-2 (Amin, Amin2) + key for Amin
      const bool n0 = l23 < l01;
      const float mn0 = fminf(l01, l23);
      const int mnk0 = n0 ? lk23 : lk01;
      const float pr0 = n0 ? h23 : h01;
      const float ot0 = fmaxf(l01, l23);
      const bool n1 = l67 < l45;
      const float mn1 = fminf(l45, l67);
      const int mnk1 = n1 ? lk67 : lk45;
      const float pr1 = n1 ? h67 : h45;
      const float ot1 = fmaxf(l45, l67);
      const bool nf = mn1 < mn0;
      const float Aminv = fminf(mn0, mn1);
      const int AminK = nf ? mnk1 : mnk0;
      const float prW = nf ? pr1 : pr0;
      const float otW = nf ? ot1 : ot0;
      const float mnL = fmaxf(mn0, mn1);
      const float Amin2v = fminf(prW, fminf(otW, mnL));

      // analytic dots + indices
      const float dT1r = A1v + A2v;  // == exact ref dot of T1 best
      const float halfS = 0.5f * Sabs;
      const float dT2 = par ? (halfS - Aminv) : halfS;

      const int p1 = A1K & 7, p2 = A2K & 7;
      const int s1b = A1K >> 3, s2b = A2K >> 3;
      const bool o12 = p1 < p2;
      const int imn = o12 ? p1 : p2, jmx = o12 ? p2 : p1;
      const int sIb = o12 ? s1b : s2b, sJb = o12 ? s2b : s1b;
      const int pbase = imn * 7 - ((imn * (imn - 1)) >> 1) + (jmx - imn - 1);
      const int t1idx = (pbase << 2) | (sIb << 1) | sJb;

      const int mp = AminK & 7;
      const int mf = par ? (msk ^ (1 << mp)) : msk;
      const int t2idx = 112 + (mf >> 1);

      // margins (thr = 2^-20 * M = 16u*M)
      const float thr = (res2 + 2.0f * Sabs + 2.0f) * 0x1.0p-20f;
      const bool a1 = (A2v - A3v) > thr;
      const bool a2 = par ? ((Amin2v - Aminv) > thr)
                          : ((Aminv + Amin2v) > thr);
      const bool c = fabsf(dT1r - dT2) > thr;

      // pack root-decode params: one-hot pair bits, T1 signs, T2 mask, mp
      const int one = (1 << imn) | (1 << jmx);
      const int sm1 = (sIb << imn) | (sJb << jmx);

      s_[sl] = s; thr_[sl] = thr; dT1_[sl] = dT1r; dT2_[sl] = dT2;
      Amn_[sl] = Aminv; Amn2_[sl] = Amin2v;
      t1_[sl] = t1idx; t2_[sl] = t2idx;
      pk_[sl] = one | (sm1 << 8) | (mf << 16) | (mp << 24);
      a1_[sl] = a1; a2_[sl] = a2; c_[sl] = c;
      const bool pT1 = dT1r > dT2;          // margin-certified when c
      pT1_[sl] = pT1;
      bi_[sl] = pT1 ? t1idx : t2idx;
      fell_[sl] = false;
    }

    // ======== ONE rare branch region per level ========
    const bool slowAny = (!a1_[0]) | (!a2_[0]) | (!c_[0]) |
                         (!a1_[1]) | (!a2_[1]) | (!c_[1]);
    if (__any(slowAny)) {
#pragma unroll
      for (int sl = 0; sl < 2; ++sl) {
        const bool slow = (!a1_[sl]) | (!a2_[sl]) | (!c_[sl]);
        if (slow) {
          // recompute per-coord meta from rr (canonical state)
          float mg[8], h[8];
          int sb[8];
#pragma unroll
          for (int k = 0; k < 8; ++k) {
            const unsigned u = __float_as_uint(rr[sl][k]);
            mg[k] = __uint_as_float(u & 0x7fffffffu);
            sb[k] = (int)(u >> 31);
            h[k] = 0.5f * rr[sl][k];  // exact
          }
          const int msk = sb[0] | (sb[1] << 1) | (sb[2] << 2) |
                          (sb[3] << 3) | (sb[4] << 4) | (sb[5] << 5) |
                          (sb[6] << 6) | (sb[7] << 7);
          const int par = __popc(msk) & 1;
          const float s = s_[sl];

          float d1v = fmaf(-2.f, dT1_[sl], s);  // exact ref d2 (valid if a1)
          int i1v = t1_[sl];
          if (!a1_[sl]) {
            if (Amn_[sl] > thr_[sl]) {
              // 28-pair best-sign exact scan (wrong signs trail > 2thr)
              float best = 3.4028235e38f;
              int bidx = 0, ci = 0;
#pragma unroll 1
              for (int i = 0; i < 8; ++i) {
#pragma unroll 1
                for (int j = i + 1; j < 8; ++j) {
                  const float aa = mg[i] + mg[j];  // == ref fl up to sign
                  const float d = fmaf(-2.f, aa, s);
                  const int idx = (ci << 2) | (sb[i] << 1) | sb[j];
                  if (d < best) { best = d; bidx = idx; }
                  ++ci;
                }
              }
              d1v = best; i1v = bidx;
            } else {
              // full exact T1 scan (coordinate ~ 0; rare), ref order
              float best = 3.4028235e38f;
              int be = 0, ci = 0;
#pragma unroll 1
              for (int i = 0; i < 8; ++i) {
#pragma unroll 1
                for (int j = i + 1; j < 8; ++j) {
                  const float a = rr[sl][i] + rr[sl][j];
                  const float b = rr[sl][i] - rr[sl][j];
                  float d;
                  d = fmaf(-2.f, a, s);
                  if (d < best) { best = d; be = ci + 0; }
                  d = fmaf(-2.f, b, s);
                  if (d < best) { best = d; be = ci + 1; }
                  d = fmaf(2.f, b, s);
                  if (d < best) { best = d; be = ci + 2; }
                  d = fmaf(2.f, a, s);
                  if (d < best) { best = d; be = ci + 3; }
                  ci += 4;
                }
              }
              d1v = best; i1v = be;
            }
          }

          float d2v = 0.f;
          int i2v = t2_[sl];
          if (!a2_[sl]) {
            const bool cheap = par && ((Amn2_[sl] + Amn2_[sl]) > thr_[sl]);
            if (cheap) {
              // odd parity: argmin must be a SINGLE-BIT flip
              float best2 = 3.4028235e38f;
              int bt = 0;
#pragma unroll 1
              for (int k = 0; k < 8; ++k) {
                const int mk = msk ^ (1 << k);
                float v = (mk & 1) ? -h[0] : h[0];
#pragma unroll
                for (int j = 1; j < 8; ++j)
                  v = (mk & (1 << j)) ? (v - h[j]) : (v + h[j]);
                const float d = fmaf(-2.f, v, s);
                const int t = mk >> 1;
                const bool take = (d < best2) || (d == best2 && t < bt);
                best2 = take ? d : best2;
                bt = take ? t : bt;
              }
              d2v = best2; i2v = 112 + bt;
            } else {
              // full exact T2 scan (very rare), sequential fl order
              float best2 = 3.4028235e38f;
              int bt = 0;
#pragma unroll 1
              for (int t = 0; t < 128; ++t) {
                const int m = (t << 1) | (__popc(t) & 1);
                float v = (m & 1) ? -h[0] : h[0];
#pragma unroll
                for (int j = 1; j < 8; ++j)
                  v = (m & (1 << j)) ? (v - h[j]) : (v + h[j]);
                const float d = fmaf(-2.f, v, s);
                if (d < best2) { best2 = d; bt = t; }
              }
              d2v = best2; i2v = 112 + bt;
            }
          } else if (!c_[sl]) {
            // exact ref d2 of analytic T2 candidate: seq |h| sum with the
            // Amin-position term negated iff odd parity (bitwise == ref)
            const int mp = (pk_[sl] >> 24) & 7;
            const int flip = par ? mp : 8;  // 8 = never
            float v = (flip == 0) ? -(0.5f * mg[0]) : (0.5f * mg[0]);
#pragma unroll
            for (int j = 1; j < 8; ++j) {
              const float tj = 0.5f * mg[j];
              v = (flip == j) ? (v - tj) : (v + tj);
            }
            d2v = fmaf(-2.f, v, s);
          }

          // final pick (c: analytic compare; else exact, '<=' keeps T1)
          const bool pT1 = c_[sl] ? (dT1_[sl] > dT2_[sl]) : (d1v <= d2v);
          pT1_[sl] = pT1;
          bi_[sl] = pT1 ? i1v : i2v;
          const bool fl = (!a1_[sl]) | (!a2_[sl]);
          fell_[sl] = fl;
          if (fl) {
            // analytic decode invalid -> gather root from global (L2-hot)
            const float4 ra = *(const float4*)(roots + (size_t)bi_[sl] * 8);
            const float4 rb =
                *(const float4*)(roots + (size_t)bi_[sl] * 8 + 4);
            qs[sl][0] += ra.x; qs[sl][1] += ra.y;
            qs[sl][2] += ra.z; qs[sl][3] += ra.w;
            qs[sl][4] += rb.x; qs[sl][5] += rb.y;
            qs[sl][6] += rb.z; qs[sl][7] += rb.w;
#pragma unroll
            for (int k = 0; k < 8; ++k) rr[sl][k] = xr[sl][k] - qs[sl][k];
          }
        }
      }
    }

    // ======== FINISH, both slots, straight-line ========
#pragma unroll
    for (int sl = 0; sl < 2; ++sl) {
      if (act[sl]) *op[sl] = (float)bi_[sl];
      op[sl] += nrow;
      if (!fell_[sl]) {
        // root in registers (bit-identical to codebook values)
        const int one = pk_[sl] & 0xFF;
        const int sm1 = (pk_[sl] >> 8) & 0xFF;
        const int mfv = (pk_[sl] >> 16) & 0xFF;
#pragma unroll
        for (int k = 0; k < 8; ++k) {
          const float t1r =
              ((one >> k) & 1) ? (((sm1 >> k) & 1) ? -1.f : 1.f) : 0.f;
          const float t2r = ((mfv >> k) & 1) ? -0.5f : 0.5f;
          qs[sl][k] += pT1_[sl] ? t1r : t2r;
        }
#pragma unroll
        for (int k = 0; k < 8; ++k) rr[sl][k] = xr[sl][k] - qs[sl][k];
      }
    }
  }

  // ======== epilogue: ste store + qerr partials ========
  float e[2] = {0.f, 0.f};
#pragma unroll
  for (int sl = 0; sl < 2; ++sl) {
    if (act[sl]) {
      float o[8];
#pragma unroll
      for (int k = 0; k < 8; ++k) o[k] = (qs[sl][k] + xr[sl][k]) - xr[sl][k];
      const int rw = sl ? row1 : row0;
      *(float4*)(out + (size_t)rw * 8) = make_float4(o[0], o[1], o[2], o[3]);
      *(float4*)(out + (size_t)rw * 8 + 4) =
          make_float4(o[4], o[5], o[6], o[7]);
#pragma unroll
      for (int k = 0; k < 8; ++k) e[sl] = fmaf(rr[sl][k], rr[sl][k], e[sl]);
    }
  }

  // two partials, bit-identical to the verified 1-row/thread scheme
  float e0 = e[0], e1 = e[1];
#pragma unroll
  for (int off = 32; off > 0; off >>= 1) e0 += __shfl_down(e0, off, 64);
#pragma unroll
  for (int off = 32; off > 0; off >>= 1) e1 += __shfl_down(e1, off, 64);
  const int lane = threadIdx.x & 63, wv = threadIdx.x >> 6;
  if (lane == 0) { wredA[wv] = e0; wredB[wv] = e1; }
  __syncthreads();
  if (threadIdx.x == 0) {
    partials[2 * blockIdx.x] = (wredA[0] + wredA[1]) + (wredA[2] + wredA[3]);
    partials[2 * blockIdx.x + 1] =
        (wredB[0] + wredB[1]) + (wredB[2] + wredB[3]);
  }
}

__global__ __launch_bounds__(256) void qerr_reduce_kernel(
    const float* __restrict__ partials, float* __restrict__ out, int n,
    size_t pos, float scale) {
#pragma clang fp contract(off)
  __shared__ float wred[4];
  float e = 0.f;
  for (int i = threadIdx.x; i < n; i += 256) e += partials[i];
#pragma unroll
  for (int off = 32; off > 0; off >>= 1) e += __shfl_down(e, off, 64);
  const int lane = threadIdx.x & 63, wv = threadIdx.x >> 6;
  if (lane == 0) wred[wv] = e;
  __syncthreads();
  if (threadIdx.x == 0)
    out[pos] = ((wred[0] + wred[1]) + (wred[2] + wred[3])) * scale;
}

extern "C" void kernel_launch(void* const* d_in, const int* in_sizes, int n_in,
                              void* d_out, int out_size, void* d_ws,
                              size_t ws_size, hipStream_t stream) {
  const float* x = (const float*)d_in[0];
  const float* roots = (const float*)d_in[1];
  float* out = (float*)d_out;
  float* partials = (float*)d_ws;

  const int nrow = in_sizes[0] / 8;
  const int nblocks = (nrow + 511) / 512;  // 512 rows per block (2/thread)

  e8_quant_kernel<<<nblocks, 256, 0, stream>>>(x, roots, out, partials, nrow);

  const size_t qerr_pos = (size_t)nrow * 12;
  const float scale = 1.0f / (float)((size_t)nrow * 8);  // 1/2^22, exact
  qerr_reduce_kernel<<<1, 256, 0, stream>>>(partials, out, 2 * nblocks,
                                            qerr_pos, scale);
}

// Round 10
// 87.980 us; speedup vs baseline: 1.1114x; 1.1114x over previous
//
#include <hip/hip_runtime.h>
#include <math.h>

// Residual 4-level E8-root VQ — analytic argmin + decomposed exact fallbacks.
// R10: 1 row/thread, straight-line hot path, ONE __any gate per level,
// in-register root build, no LDS codebook (global gather on rare fallback).
//
// Outputs (concat, all float32 in d_out):
//   [0, 8N)          quantized_ste = (qsum + x) - x   (matches jnp rounding)
//   [8N, 12N)        idx_stack[4][N] as float (values 0..239)
//   [12N]            qerr = mean((x - qsum)^2)
//
// ---- Analytic argmin (R4/R5, verified absmax=0) ----
// Reference: d2[j] = fl(fl(res2+2) - fl(2*dot_j)), dot_j sequential k=0..7;
// argmin, first-index tie-break on ROUNDED values.
//   T1 best: two largest |r_k| (A1,A2), signs of those coords.
//   T2 best: sign mask of r; odd parity flips the smallest-|r_k| bit.
// Error budget (u = 2^-24, M = res2 + 2 + 2*Sabs): ref d2 deviates from
// analytic by <= 2.75u*M; compare slop <= 5.5u*M; margin measurement error
// <= 3.5u*M. thr = 2^-20*M = 16u*M: passing margin -> true gap >= 12.5u*M
// > 5.5u*M -> rounding can neither reorder nor create a rounded tie.
//
// ---- Fallback decomposition (R6/R7, verified absmax=0) ----
//   !a1: if Amin > thr -> 28-pair best-sign EXACT scan (wrong signs trail by
//        2*Amin > 2thr); else full 112 exact scan.
//   !a2 odd: if 2*Amin2 > thr -> argmin is a SINGLE-BIT flip, 8 exact
//        seq-sum d2s, tie-break smaller t; else full 128 scan (rolled).
//   !a2 even: full 128 scan.
//   !c with a2: exact ref d2 of analytic T2 candidate (seq |h| sum, Amin
//        term negated iff odd parity; bitwise == reference).
//   pick: c ? (dT1>dT2 ? i1:i2) : (d1<=d2x ? i1:i2)  ('<=' == first-index).
//
// ---- R10 structure rationale ----
// R9 (2-slot merged region) regressed: carrying both slots' analytic
// temporaries across the gate likely crossed the VGPR-128 occupancy cliff
// (m69: waves/SIMD halve at 64/128/256). R10 keeps R9's verified single-gate
// logic at ONE slot: small live state, 2048 blocks for cross-wave latency
// hiding, hot path from res2 to root-update is one basic block when no lane
// needs a fallback. Roots built in registers (bit-identical values, R8-
// verified); LDS only for the 16-B qerr wred.
//
// ---- Exact-path numerics (verified absmax=0 R1/R4/R5/R7/R8/R9) ----
//  - r2[j] == 2.0 exactly; d2 = fmaf(+-2, dot, s) == fl(s - fl(2*dot)).
//  - clip(.,0) dropped: at most one root can have rounded d2 <= 0.
//  - res2: numpy pairwise tree; fp contract OFF everywhere.
//  - qerr partials: R1-verified per-block scheme (bit-identical array).

__global__ __launch_bounds__(256) void e8_quant_kernel(
    const float* __restrict__ x, const float* __restrict__ roots,
    float* __restrict__ out, float* __restrict__ partials, int nrow) {
#pragma clang fp contract(off)
  __shared__ float wred[4];

  const int row = blockIdx.x * 256 + threadIdx.x;
  const bool act = row < nrow;
  const int rl = act ? row : nrow - 1;  // clamp: compute real data, no branch
  float* out_idx = out + (size_t)nrow * 8;

  float xr[8], qs[8], rr[8];
  {
    const float4 xa = *(const float4*)(x + (size_t)rl * 8);
    const float4 xb = *(const float4*)(x + (size_t)rl * 8 + 4);
    xr[0] = xa.x; xr[1] = xa.y; xr[2] = xa.z; xr[3] = xa.w;
    xr[4] = xb.x; xr[5] = xb.y; xr[6] = xb.z; xr[7] = xb.w;
#pragma unroll
    for (int k = 0; k < 8; ++k) { qs[k] = 0.f; rr[k] = xr[k]; }
  }

#pragma unroll 1
  for (int lvl = 0; lvl < 4; ++lvl) {
    // ======== analytic hot path (straight-line) ========
    float q[8];
#pragma unroll
    for (int k = 0; k < 8; ++k) q[k] = rr[k] * rr[k];
    const float res2 = ((q[0] + q[1]) + (q[2] + q[3])) +
                       ((q[4] + q[5]) + (q[6] + q[7]));
    const float s = res2 + 2.0f;

    float mg[8];
    int sb[8];
#pragma unroll
    for (int k = 0; k < 8; ++k) {
      const unsigned u = __float_as_uint(rr[k]);
      mg[k] = __uint_as_float(u & 0x7fffffffu);
      sb[k] = (int)(u >> 31);
    }
    const int msk = sb[0] | (sb[1] << 1) | (sb[2] << 2) | (sb[3] << 3) |
                    (sb[4] << 4) | (sb[5] << 5) | (sb[6] << 6) | (sb[7] << 7);
    const int par = __popc(msk) & 1;
    const float Sabs = ((mg[0] + mg[1]) + (mg[2] + mg[3])) +
                       ((mg[4] + mg[5]) + (mg[6] + mg[7]));

    const int K0 = 0 | (sb[0] << 3), K1 = 1 | (sb[1] << 3),
              K2 = 2 | (sb[2] << 3), K3 = 3 | (sb[3] << 3),
              K4 = 4 | (sb[4] << 3), K5 = 5 | (sb[5] << 3),
              K6 = 6 | (sb[6] << 3), K7 = 7 | (sb[7] << 3);

    // top-3 (A1>=A2>=A3) + keys for A1,A2
    const bool g01 = mg[1] > mg[0];
    const float h01 = fmaxf(mg[0], mg[1]), l01 = fminf(mg[0], mg[1]);
    const int hk01 = g01 ? K1 : K0, lk01 = g01 ? K0 : K1;
    const bool g23 = mg[3] > mg[2];
    const float h23 = fmaxf(mg[2], mg[3]), l23 = fminf(mg[2], mg[3]);
    const int hk23 = g23 ? K3 : K2, lk23 = g23 ? K2 : K3;
    const bool g45 = mg[5] > mg[4];
    const float h45 = fmaxf(mg[4], mg[5]), l45 = fminf(mg[4], mg[5]);
    const int hk45 = g45 ? K5 : K4, lk45 = g45 ? K4 : K5;
    const bool g67 = mg[7] > mg[6];
    const float h67 = fmaxf(mg[6], mg[7]), l67 = fminf(mg[6], mg[7]);
    const int hk67 = g67 ? K7 : K6, lk67 = g67 ? K6 : K7;
    const bool qg0 = h23 > h01;
    const float qh0 = fmaxf(h01, h23);
    const int qhk0 = qg0 ? hk23 : hk01;
    const float sA0 = qg0 ? l23 : l01;
    const int sAk0 = qg0 ? lk23 : lk01;
    const float sB0 = qg0 ? h01 : h23;
    const int sBk0 = qg0 ? hk01 : hk23;
    const float loL0 = qg0 ? l01 : l23;
    const bool qx0 = sB0 > sA0;
    const float qs0v = fmaxf(sA0, sB0);
    const int qsk0 = qx0 ? sBk0 : sAk0;
    const float qt0 = qx0 ? fmaxf(sA0, loL0) : sB0;
    const bool qg1 = h67 > h45;
    const float qh1 = fmaxf(h45, h67);
    const int qhk1 = qg1 ? hk67 : hk45;
    const float sA1 = qg1 ? l67 : l45;
    const int sAk1 = qg1 ? lk67 : lk45;
    const float sB1 = qg1 ? h45 : h67;
    const int sBk1 = qg1 ? hk45 : hk67;
    const float loL1 = qg1 ? l45 : l67;
    const bool qx1 = sB1 > sA1;
    const float qs1v = fmaxf(sA1, sB1);
    const int qsk1 = qx1 ? sBk1 : sAk1;
    const float qt1 = qx1 ? fmaxf(sA1, loL1) : sB1;
    const bool fg = qh1 > qh0;
    const float A1v = fmaxf(qh0, qh1);
    const int A1K = fg ? qhk1 : qhk0;
    const float fA = fg ? qs1v : qs0v;
    const int fAk = fg ? qsk1 : qsk0;
    const float fB = fg ? qh0 : qh1;
    const int fBk = fg ? qhk0 : qhk1;
    const float tW = fg ? qt1 : qt0;
    const float sL = fg ? qs0v : qs1v;
    const bool fh = fB > fA;
    const float A2v = fmaxf(fA, fB);
    const int A2K = fh ? fBk : fAk;
    const float A3v = fh ? fmaxf(fA, sL) : fmaxf(tW, fB);

    // bottom-2 (Amin, Amin2) + key for Amin
    const bool n0 = l23 < l01;
    const float mn0 = fminf(l01, l23);
    const int mnk0 = n0 ? lk23 : lk01;
    const float pr0 = n0 ? h23 : h01;
    const float ot0 = fmaxf(l01, l23);
    const bool n1 = l67 < l45;
    const float mn1 = fminf(l45, l67);
    const int mnk1 = n1 ? lk67 : lk45;
    const float pr1 = n1 ? h67 : h45;
    const float ot1 = fmaxf(l45, l67);
    const bool nf = mn1 < mn0;
    const float Aminv = fminf(mn0, mn1);
    const int AminK = nf ? mnk1 : mnk0;
    const float prW = nf ? pr1 : pr0;
    const float otW = nf ? ot1 : ot0;
    const float mnL = fmaxf(mn0, mn1);
    const float Amin2v = fminf(prW, fminf(otW, mnL));

    // analytic dots + indices
    const float dT1r = A1v + A2v;  // == exact ref dot of T1 best (1 round)
    const float halfS = 0.5f * Sabs;
    const float dT2 = par ? (halfS - Aminv) : halfS;

    const int p1 = A1K & 7, p2 = A2K & 7;
    const int s1b = A1K >> 3, s2b = A2K >> 3;
    const bool o12 = p1 < p2;
    const int imn = o12 ? p1 : p2, jmx = o12 ? p2 : p1;
    const int sIb = o12 ? s1b : s2b, sJb = o12 ? s2b : s1b;
    const int pbase = imn * 7 - ((imn * (imn - 1)) >> 1) + (jmx - imn - 1);
    const int t1idx = (pbase << 2) | (sIb << 1) | sJb;

    const int mp = AminK & 7;
    const int mf = par ? (msk ^ (1 << mp)) : msk;
    const int t2idx = 112 + (mf >> 1);

    // margins (thr = 2^-20 * M = 16u*M)
    const float thr = (res2 + 2.0f * Sabs + 2.0f) * 0x1.0p-20f;
    const bool a1 = (A2v - A3v) > thr;
    const bool a2 = par ? ((Amin2v - Aminv) > thr)
                        : ((Aminv + Amin2v) > thr);
    const bool c = fabsf(dT1r - dT2) > thr;

    bool pT1 = dT1r > dT2;  // margin-certified when c
    int bi = pT1 ? t1idx : t2idx;
    bool fell = false;

    // ======== ONE rare gate per level ========
    const bool slow = (!a1) | (!a2) | (!c);
    if (__any(slow)) {
      if (slow) {
        float h[8];
#pragma unroll
        for (int k = 0; k < 8; ++k) h[k] = 0.5f * rr[k];  // exact

        float d1v = fmaf(-2.f, dT1r, s);  // exact ref d2 of t1idx (if a1)
        int i1v = t1idx;
        if (!a1) {
          if (Aminv > thr) {
            // 28-pair best-sign exact scan (wrong signs trail > 2thr)
            float best = 3.4028235e38f;
            int bidx = 0, ci = 0;
#pragma unroll
            for (int i = 0; i < 8; ++i) {
#pragma unroll
              for (int j = i + 1; j < 8; ++j) {
                const float aa = mg[i] + mg[j];  // == ref fl(ri+rj), |sign|
                const float d = fmaf(-2.f, aa, s);
                const int idx = (ci << 2) | (sb[i] << 1) | sb[j];
                if (d < best) { best = d; bidx = idx; }
                ++ci;
              }
            }
            d1v = best; i1v = bidx;
          } else {
            // full exact T1 scan (a coordinate ~ 0; rare), ref order
            float best = 3.4028235e38f;
            int be = 0, ci = 0;
#pragma unroll
            for (int i = 0; i < 8; ++i) {
#pragma unroll
              for (int j = i + 1; j < 8; ++j) {
                const float a = rr[i] + rr[j];
                const float b = rr[i] - rr[j];
                float d;
                d = fmaf(-2.f, a, s);
                if (d < best) { best = d; be = ci + 0; }
                d = fmaf(-2.f, b, s);
                if (d < best) { best = d; be = ci + 1; }
                d = fmaf(2.f, b, s);
                if (d < best) { best = d; be = ci + 2; }
                d = fmaf(2.f, a, s);
                if (d < best) { best = d; be = ci + 3; }
                ci += 4;
              }
            }
            d1v = best; i1v = be;
          }
        }

        float d2v = 0.f;
        int i2v = t2idx;
        if (!a2) {
          const bool cheap = par && ((Amin2v + Amin2v) > thr);
          if (cheap) {
            // odd parity: argmin must be a SINGLE-BIT flip
            float best2 = 3.4028235e38f;
            int bt = 0;
#pragma unroll
            for (int k = 0; k < 8; ++k) {
              const int mk = msk ^ (1 << k);
              float v = (mk & 1) ? -h[0] : h[0];
#pragma unroll
              for (int j = 1; j < 8; ++j)
                v = (mk & (1 << j)) ? (v - h[j]) : (v + h[j]);
              const float d = fmaf(-2.f, v, s);
              const int t = mk >> 1;
              const bool take = (d < best2) || (d == best2 && t < bt);
              best2 = take ? d : best2;
              bt = take ? t : bt;
            }
            d2v = best2; i2v = 112 + bt;
          } else {
            // full exact T2 scan (very rare), sequential fl order
            float best2 = 3.4028235e38f;
            int bt = 0;
#pragma unroll 1
            for (int t = 0; t < 128; ++t) {
              const int m = (t << 1) | (__popc(t) & 1);
              float v = (m & 1) ? -h[0] : h[0];
#pragma unroll
              for (int j = 1; j < 8; ++j)
                v = (m & (1 << j)) ? (v - h[j]) : (v + h[j]);
              const float d = fmaf(-2.f, v, s);
              if (d < best2) { best2 = d; bt = t; }
            }
            d2v = best2; i2v = 112 + bt;
          }
        } else if (!c) {
          // exact ref d2 of analytic T2 candidate: seq |h| sum with the
          // Amin-position term negated iff odd parity (bitwise == ref)
          const int flip = par ? mp : 8;  // 8 = never
          float v = (flip == 0) ? -(0.5f * mg[0]) : (0.5f * mg[0]);
#pragma unroll
          for (int j = 1; j < 8; ++j) {
            const float tj = 0.5f * mg[j];
            v = (flip == j) ? (v - tj) : (v + tj);
          }
          d2v = fmaf(-2.f, v, s);
        }

        // final pick (c: analytic compare; else exact, '<=' keeps T1)
        pT1 = c ? (dT1r > dT2) : (d1v <= d2v);
        bi = pT1 ? i1v : i2v;
        fell = (!a1) | (!a2);
        if (fell) {
          // analytic decode invalid -> gather root from global (L2-hot)
          const float4 ra = *(const float4*)(roots + (size_t)bi * 8);
          const float4 rb = *(const float4*)(roots + (size_t)bi * 8 + 4);
          qs[0] += ra.x; qs[1] += ra.y; qs[2] += ra.z; qs[3] += ra.w;
          qs[4] += rb.x; qs[5] += rb.y; qs[6] += rb.z; qs[7] += rb.w;
#pragma unroll
          for (int k = 0; k < 8; ++k) rr[k] = xr[k] - qs[k];
        }
      }
    }

    if (act) out_idx[(size_t)lvl * nrow + row] = (float)bi;

    // ======== root in registers (bit-identical to codebook values) ========
    if (!fell) {
#pragma unroll
      for (int k = 0; k < 8; ++k) {
        const float t1r = (k == imn) ? (sIb ? -1.f : 1.f)
                                     : ((k == jmx) ? (sJb ? -1.f : 1.f) : 0.f);
        const float t2r = ((mf >> k) & 1) ? -0.5f : 0.5f;
        qs[k] += pT1 ? t1r : t2r;
      }
#pragma unroll
      for (int k = 0; k < 8; ++k) rr[k] = xr[k] - qs[k];
    }
  }

  // ======== epilogue: ste store + qerr partial (R1-verified scheme) ========
  float e = 0.f;
  if (act) {
    float o[8];
#pragma unroll
    for (int k = 0; k < 8; ++k) o[k] = (qs[k] + xr[k]) - xr[k];
    *(float4*)(out + (size_t)row * 8) = make_float4(o[0], o[1], o[2], o[3]);
    *(float4*)(out + (size_t)row * 8 + 4) = make_float4(o[4], o[5], o[6], o[7]);
#pragma unroll
    for (int k = 0; k < 8; ++k) e = fmaf(rr[k], rr[k], e);
  }

#pragma unroll
  for (int off = 32; off > 0; off >>= 1) e += __shfl_down(e, off, 64);
  const int lane = threadIdx.x & 63, wv = threadIdx.x >> 6;
  if (lane == 0) wred[wv] = e;
  __syncthreads();
  if (threadIdx.x == 0)
    partials[blockIdx.x] = (wred[0] + wred[1]) + (wred[2] + wred[3]);
}

__global__ __launch_bounds__(256) void qerr_reduce_kernel(
    const float* __restrict__ partials, float* __restrict__ out, int n,
    size_t pos, float scale) {
#pragma clang fp contract(off)
  __shared__ float wred[4];
  float e = 0.f;
  for (int i = threadIdx.x; i < n; i += 256) e += partials[i];
#pragma unroll
  for (int off = 32; off > 0; off >>= 1) e += __shfl_down(e, off, 64);
  const int lane = threadIdx.x & 63, wv = threadIdx.x >> 6;
  if (lane == 0) wred[wv] = e;
  __syncthreads();
  if (threadIdx.x == 0)
    out[pos] = ((wred[0] + wred[1]) + (wred[2] + wred[3])) * scale;
}

extern "C" void kernel_launch(void* const* d_in, const int* in_sizes, int n_in,
                              void* d_out, int out_size, void* d_ws,
                              size_t ws_size, hipStream_t stream) {
  const float* x = (const float*)d_in[0];
  const float* roots = (const float*)d_in[1];
  float* out = (float*)d_out;
  float* partials = (float*)d_ws;

  const int nrow = in_sizes[0] / 8;
  const int nblocks = (nrow + 255) / 256;

  e8_quant_kernel<<<nblocks, 256, 0, stream>>>(x, roots, out, partials, nrow);

  const size_t qerr_pos = (size_t)nrow * 12;
  const float scale = 1.0f / (float)((size_t)nrow * 8);  // 1/2^22, exact
  qerr_reduce_kernel<<<1, 256, 0, stream>>>(partials, out, nblocks, qerr_pos,
                                            scale);
}